// Round 7
// baseline (280.980 us; speedup 1.0000x reference)
//
#include <hip/hip_runtime.h>
#include <math.h>

// Problem constants (fixed by reference)
#define BB   16
#define LATD 8
#define NN   500000
#define XSZ  256
#define HALF 128
#define IMG_ELEMS (BB * XSZ * XSZ)          // 1,048,576 floats
#define FREQ_COLS 129                        // XS/2+1
#define NBLK ((NN + 255) / 256)              // 1954 point-blocks

// Entry packing: bits[11:0] = pixel-in-tile, bits[31:12] = top 20 bits of the
// fp32 value (round-to-nearest on the dropped 12 mantissa bits).
__device__ __forceinline__ unsigned pack_entry(float v, int off12) {
    unsigned pv = (__float_as_uint(v) + 0x800u) & 0xFFFFF000u;
    return pv | (unsigned)off12;
}
__device__ __forceinline__ float entry_val(unsigned e) {
    return __uint_as_float(e & 0xFFFFF000u);
}

// ---------------------------------------------------------------------------
// wave64 inclusive scan (shuffle-based, no barriers)
// ---------------------------------------------------------------------------
__device__ __forceinline__ unsigned wave_incl_scan(unsigned x, int lane) {
    #pragma unroll
    for (int d = 1; d < 64; d <<= 1) {
        unsigned y = __shfl_up(x, d, 64);
        if (lane >= d) x += y;
    }
    return x;
}

// ---------------------------------------------------------------------------
// K0: per-image prep — rotation rows 0/1, shifts+half, SIREN MLP hidden h[8]
// ---------------------------------------------------------------------------
__global__ void prep_kernel(const float* __restrict__ rows,
                            const float* __restrict__ shifts,
                            const float* __restrict__ latent,
                            const float* __restrict__ W0, const float* __restrict__ b0,
                            const float* __restrict__ W1, const float* __restrict__ b1,
                            const float* __restrict__ W2, const float* __restrict__ b2,
                            const float* __restrict__ W3, const float* __restrict__ b3,
                            float* __restrict__ bdata) {
    int b = threadIdx.x;
    if (b >= BB) return;

    float rot  = rows[b * 3 + 0];
    float tilt = rows[b * 3 + 1];
    float psi  = rows[b * 3 + 2];
    float ca, sa, cb, sb, cg, sg;
    sincosf(rot, &sa, &ca);
    sincosf(tilt, &sb, &cb);
    sincosf(psi, &sg, &cg);

    float R00 =  cg * cb * ca - sg * sa;
    float R01 =  cg * cb * sa + sg * ca;
    float R02 = -cg * sb;
    float R10 = -sg * cb * ca - cg * sa;
    float R11 = -sg * cb * sa + cg * ca;
    float R12 =  sg * sb;

    float h[LATD], t[LATD];
    #pragma unroll
    for (int j = 0; j < LATD; ++j) {
        float acc = b0[j];
        #pragma unroll
        for (int l = 0; l < LATD; ++l) acc += latent[b * LATD + l] * W0[l * LATD + j];
        t[j] = acc;
    }
    #pragma unroll
    for (int j = 0; j < LATD; ++j) h[j] = sinf(30.0f * t[j]);

    const float* Ws[3] = {W1, W2, W3};
    const float* bs[3] = {b1, b2, b3};
    for (int L = 0; L < 3; ++L) {
        #pragma unroll
        for (int j = 0; j < LATD; ++j) {
            float acc = bs[L][j];
            #pragma unroll
            for (int l = 0; l < LATD; ++l) acc += h[l] * Ws[L][l * LATD + j];
            t[j] = acc;
        }
        #pragma unroll
        for (int j = 0; j < LATD; ++j) h[j] += sinf(t[j]);
    }

    float* P = bdata + b * 16;
    P[0] = R00; P[1] = R01; P[2] = R02;
    P[3] = R10; P[4] = R11; P[5] = R12;
    P[6] = shifts[b * 2 + 0] + (float)HALF;
    P[7] = shifts[b * 2 + 1] + (float)HALF;
    #pragma unroll
    for (int j = 0; j < LATD; ++j) P[8 + j] = h[j];
}

__device__ __forceinline__ int2 project_px(const float* __restrict__ Q,
                                           float cx, float cy, float cz) {
    float x = fmaf(Q[0], cx, fmaf(Q[1], cy, fmaf(Q[2], cz, Q[6])));
    float y = fmaf(Q[3], cx, fmaf(Q[4], cy, fmaf(Q[5], cz, Q[7])));
    float px = fminf(fmaxf(rintf(x), 0.f), 255.f);
    float py = fminf(fmaxf(rintf(y), 0.f), 255.f);
    return make_int2((int)px, (int)py);
}

// ---------------------------------------------------------------------------
// K1: fill2 — ATOMIC-FREE binning. Each block owns a fixed 4096-entry bucket
// segment. Per image: 4-ballot multi-split on the 4-bit band id gives each
// lane its rank within its (wave, tile) group; group leaders record counts
// (non-atomic LDS). A 256-wide shuffle scan turns per-tile block totals into
// a tile-sorted layout. Writes: contiguous bucket segment + lbaseT[t][blk]
// offset table (row 256 = block entry count).
// ---------------------------------------------------------------------------
__global__ __launch_bounds__(256) void fill2_kernel(
        const float* __restrict__ coords, const float* __restrict__ values,
        const float* __restrict__ Wd, const float* __restrict__ bd,
        const float* __restrict__ bdata, unsigned* __restrict__ bucket,
        unsigned* __restrict__ lbaseT) {
    __shared__ float    P[256];
    __shared__ unsigned wcnt[4][256];
    __shared__ unsigned owb[4][256];
    __shared__ unsigned lbase[256];
    __shared__ unsigned wsum[4];
    __shared__ unsigned stage[4096];

    int tid = threadIdx.x;
    int blk = blockIdx.x;
    int lane = tid & 63;
    int w = tid >> 6;
    P[tid] = bdata[tid];
    #pragma unroll
    for (int i = 0; i < 4; ++i) wcnt[i][tid] = 0;
    __syncthreads();

    int n = blk * 256 + tid;
    bool active = (n < NN);
    const unsigned long long below = (lane == 63) ? ~0ull >> 1
                                                  : ((1ull << lane) - 1ull);

    unsigned word[BB];
    unsigned char tl[BB];
    unsigned char rk[BB];
    if (active) {
        float cx = coords[n * 3 + 0];
        float cy = coords[n * 3 + 1];
        float cz = coords[n * 3 + 2];
        float base = values[n] + bd[n];
        float wd[LATD];
        #pragma unroll
        for (int l = 0; l < LATD; ++l) wd[l] = Wd[l * NN + n];
        unsigned long long act = __ballot(1);
        #pragma unroll
        for (int bi = 0; bi < BB; ++bi) {
            const float* Q = &P[bi * 16];
            int2 p = project_px(Q, cx, cy, cz);
            float delta = 0.f;
            #pragma unroll
            for (int l = 0; l < LATD; ++l) delta = fmaf(Q[8 + l], wd[l], delta);
            int band = p.y >> 4;
            int tile = bi * 16 + band;
            int off12 = ((p.y & 15) << 8) | p.x;
            word[bi] = pack_entry(base + delta, off12);
            tl[bi] = (unsigned char)tile;
            // 4-ballot multi-split on band bits
            unsigned long long m0 = __ballot(band & 1);
            unsigned long long m1 = __ballot(band & 2);
            unsigned long long m2 = __ballot(band & 4);
            unsigned long long m3 = __ballot(band & 8);
            unsigned long long meq = ((band & 1) ? m0 : ~m0)
                                   & ((band & 2) ? m1 : ~m1)
                                   & ((band & 4) ? m2 : ~m2)
                                   & ((band & 8) ? m3 : ~m3) & act;
            unsigned r = (unsigned)__popcll(meq & below);
            rk[bi] = (unsigned char)r;
            if (r == 0) wcnt[w][tile] = (unsigned)__popcll(meq);  // leader
        }
    }
    __syncthreads();

    // per-tile wave offsets + block-level exclusive scan (tid == tile id)
    unsigned c0 = wcnt[0][tid], c1 = wcnt[1][tid], c2 = wcnt[2][tid], c3 = wcnt[3][tid];
    owb[0][tid] = 0;
    owb[1][tid] = c0;
    owb[2][tid] = c0 + c1;
    owb[3][tid] = c0 + c1 + c2;
    unsigned btot = c0 + c1 + c2 + c3;
    unsigned s = wave_incl_scan(btot, lane);
    if (lane == 63) wsum[w] = s;
    __syncthreads();
    unsigned off = 0;
    #pragma unroll
    for (int i = 0; i < 4; ++i) { unsigned u = wsum[i]; if (i < w) off += u; }
    unsigned excl = s + off - btot;
    lbase[tid] = excl;
    __syncthreads();

    if (active) {
        #pragma unroll
        for (int bi = 0; bi < BB; ++bi) {
            unsigned t = tl[bi];
            stage[lbase[t] + owb[w][t] + rk[bi]] = word[bi];
        }
    }
    __syncthreads();

    int nactive = NN - blk * 256;
    if (nactive > 256) nactive = 256;
    int tot = nactive * BB;
    unsigned* seg = bucket + ((size_t)blk << 12);
    for (int i = tid; i < tot; i += 256) seg[i] = stage[i];
    lbaseT[(size_t)tid * NBLK + blk] = lbase[tid];
    if (tid == 0) lbaseT[(size_t)256 * NBLK + blk] = (unsigned)tot;
}

// ---------------------------------------------------------------------------
// K2: accum2 — block (t,m) accumulates runs of tile t from a slice of blocks
// into a private LDS tile (LDS atomics — the remaining 8M-lane floor), then
// writes a PARTIAL tile; fft_rows_fwd sums the M partials.
// ---------------------------------------------------------------------------
__global__ __launch_bounds__(256) void accum2_kernel(
        const unsigned* __restrict__ bucket, const unsigned* __restrict__ lbaseT,
        float* __restrict__ partials, int M) {
    __shared__ float tile[4096];
    int t = blockIdx.x & 255;
    int m = blockIdx.x >> 8;
    int tid = threadIdx.x;
    #pragma unroll
    for (int i = 0; i < 16; ++i) tile[tid + (i << 8)] = 0.f;
    __syncthreads();
    int blk0 = (int)((long long)NBLK * m / M);
    int blk1 = (int)((long long)NBLK * (m + 1) / M);
    const unsigned* row0 = lbaseT + (size_t)t * NBLK;
    const unsigned* row1 = lbaseT + (size_t)(t + 1) * NBLK;
    for (int blk = blk0 + tid; blk < blk1; blk += 256) {
        unsigned s = row0[blk];
        unsigned e = row1[blk];
        const unsigned* bp = bucket + ((size_t)blk << 12);
        for (unsigned i = s; i < e; ++i) {
            unsigned w = bp[i];
            atomicAdd(&tile[w & 4095u], entry_val(w));
        }
    }
    __syncthreads();
    float4* dst = (float4*)(partials + (((size_t)m * 256 + t) << 12));
    const float4* src = (const float4*)tile;
    for (int i = tid; i < 1024; i += 256) dst[i] = src[i];
}

// ---------------------------------------------------------------------------
// Fallback: device-scope atomic scatter (R1 path) + zero
// ---------------------------------------------------------------------------
__global__ void zero_kernel(float4* __restrict__ p, int n4) {
    int i = blockIdx.x * blockDim.x + threadIdx.x;
    if (i < n4) p[i] = make_float4(0.f, 0.f, 0.f, 0.f);
}

__global__ __launch_bounds__(256) void scatter_atomic_kernel(
        const float* __restrict__ coords, const float* __restrict__ values,
        const float* __restrict__ Wd, const float* __restrict__ bd,
        const float* __restrict__ bdata, float* __restrict__ img) {
    __shared__ float P[BB * 16];
    P[threadIdx.x] = bdata[threadIdx.x];
    __syncthreads();
    int n = blockIdx.x * 256 + threadIdx.x;
    if (n >= NN) return;
    float cx = coords[n * 3 + 0];
    float cy = coords[n * 3 + 1];
    float cz = coords[n * 3 + 2];
    float base = values[n] + bd[n];
    float wd[LATD];
    #pragma unroll
    for (int l = 0; l < LATD; ++l) wd[l] = Wd[l * NN + n];
    #pragma unroll
    for (int b = 0; b < BB; ++b) {
        const float* Q = &P[b * 16];
        int2 p = project_px(Q, cx, cy, cz);
        float delta = 0.f;
        #pragma unroll
        for (int l = 0; l < LATD; ++l) delta = fmaf(Q[8 + l], wd[l], delta);
        atomicAdd(img + ((b << 16) | (p.y << 8) | p.x), base + delta);
    }
}

// ---------------------------------------------------------------------------
// Gaussian 7-tap weights (sigma=1, radius=3, normalized)
// ---------------------------------------------------------------------------
__device__ __constant__ float GW[4] = {0.39905027f, 0.24203623f, 0.05400558f, 0.00443305f};

// ---------------------------------------------------------------------------
// 256-point complex Stockham FFT in LDS, one 64-lane slice per FFT.
// ---------------------------------------------------------------------------
__device__ __forceinline__ void fft256(float2* src, float2* dst,
                                       const float2* __restrict__ TW,
                                       int lane, float dir) {
    #pragma unroll
    for (int t = 0; t < 8; ++t) {
        const int s = 1 << t;
        #pragma unroll
        for (int r = 0; r < 2; ++r) {
            int i = lane + (r << 6);
            int q = i & (s - 1);
            int p = i >> t;
            float2 a = src[q + s * p];
            float2 b = src[q + s * p + 128];
            int m = p << t;
            float cs = TW[m].x;
            float sn = dir * TW[m].y;
            float2 sum = make_float2(a.x + b.x, a.y + b.y);
            float dx = a.x - b.x;
            float dy = a.y - b.y;
            float2 tw = make_float2(dx * cs - dy * sn, dx * sn + dy * cs);
            int o = q + ((p * s) << 1);
            dst[o] = sum;
            dst[o + s] = tw;
        }
        __syncthreads();
        float2* tmp = src; src = dst; dst = tmp;
    }
}

__device__ __forceinline__ void fill_tw256(float2* TW, int tid) {
    if (tid < 128) {
        float sn, cs;
        sincosf(0.0245436926061703f * (float)tid, &sn, &cs);
        TW[tid] = make_float2(cs, sn);
    }
}

// ---------------------------------------------------------------------------
// K3: (sum M partials) + x-blur + forward row rFFT, 4 rows per block.
// ---------------------------------------------------------------------------
__global__ __launch_bounds__(256) void fft_rows_fwd(const float* __restrict__ img,
                                                    const float* __restrict__ partials,
                                                    int M,
                                                    float2* __restrict__ Freq) {
    __shared__ float2 bufA[4][256];
    __shared__ float2 bufB[4][256];
    __shared__ float2 TW[128];
    __shared__ float  rowr[4][256];
    int tid = threadIdx.x;
    int lane = tid & 63;
    int sub = tid >> 6;
    fill_tw256(TW, tid);
    int b  = blockIdx.x >> 6;
    int y0 = (blockIdx.x & 63) << 2;

    if (M > 0) {
        int t = (b << 4) | (y0 >> 4);
        const float* pb = partials + ((size_t)t << 12) + ((y0 & 15) << 8);
        const size_t mstr = (size_t)256 << 12;
        for (int i = tid; i < 1024; i += 256) {
            float s = 0.f;
            for (int m = 0; m < M; ++m) s += pb[(size_t)m * mstr + i];
            ((float*)rowr)[i] = s;
        }
    } else {
        const float* src = img + (((size_t)(b << 8) + y0) << 8);
        for (int i = tid; i < 1024; i += 256) ((float*)rowr)[i] = src[i];
    }
    __syncthreads();

    #pragma unroll
    for (int j = 0; j < 4; ++j) {
        int x = lane + (j << 6);
        float acc = GW[0] * rowr[sub][x];
        #pragma unroll
        for (int t = 1; t <= 3; ++t) {
            if (x - t >= 0)  acc += GW[t] * rowr[sub][x - t];
            if (x + t < 256) acc += GW[t] * rowr[sub][x + t];
        }
        bufA[sub][x] = make_float2(acc, 0.f);
    }
    __syncthreads();
    fft256(bufA[sub], bufB[sub], TW, lane, -1.f);

    for (int i = tid; i < FREQ_COLS * 4; i += 256) {
        int col = i >> 2;
        int s   = i & 3;
        Freq[((size_t)(b * FREQ_COLS + col) << 8) + y0 + s] = bufA[s][col];
    }
}

// ---------------------------------------------------------------------------
// K4: column pass — y-blur (complex) + FFT + CTF + inverse FFT, 4 cols/block.
// ---------------------------------------------------------------------------
__global__ __launch_bounds__(256) void fft_cols_ctf(float2* __restrict__ Freq,
                                                    const float* __restrict__ ctf) {
    __shared__ float2 bufA[4][256];
    __shared__ float2 bufB[4][256];
    __shared__ float2 TW[128];
    int tid = threadIdx.x;
    int lane = tid & 63;
    int sub = tid >> 6;
    fill_tw256(TW, tid);
    int b  = blockIdx.x / 33;
    int c0 = (blockIdx.x - b * 33) << 2;
    int col  = c0 + sub;
    int colc = col < FREQ_COLS ? col : (FREQ_COLS - 1);
    float2* basep = Freq + ((size_t)(b * FREQ_COLS + colc) << 8);

    #pragma unroll
    for (int j = 0; j < 4; ++j) {
        int k = lane + (j << 6);
        bufB[sub][k] = basep[k];
    }
    __syncthreads();
    #pragma unroll
    for (int j = 0; j < 4; ++j) {
        int k = lane + (j << 6);
        float ax = GW[0] * bufB[sub][k].x;
        float ay = GW[0] * bufB[sub][k].y;
        #pragma unroll
        for (int t = 1; t <= 3; ++t) {
            if (k - t >= 0)  { ax += GW[t] * bufB[sub][k - t].x; ay += GW[t] * bufB[sub][k - t].y; }
            if (k + t < 256) { ax += GW[t] * bufB[sub][k + t].x; ay += GW[t] * bufB[sub][k + t].y; }
        }
        bufA[sub][k] = make_float2(ax, ay);
    }
    __syncthreads();
    fft256(bufA[sub], bufB[sub], TW, lane, -1.f);
    #pragma unroll
    for (int j = 0; j < 4; ++j) {
        int k = lane + (j << 6);
        float c = ctf[(size_t)((b << 8) | k) * FREQ_COLS + colc];
        bufA[sub][k].x *= c;
        bufA[sub][k].y *= c;
    }
    __syncthreads();
    fft256(bufA[sub], bufB[sub], TW, lane, +1.f);
    if (col < FREQ_COLS) {
        #pragma unroll
        for (int j = 0; j < 4; ++j) {
            int k = lane + (j << 6);
            basep[k] = bufA[sub][k];
        }
    }
}

// ---------------------------------------------------------------------------
// K5: Hermitian-extend + inverse row FFT + scale, 4 rows per block.
// ---------------------------------------------------------------------------
__global__ __launch_bounds__(256) void fft_rows_inv(const float2* __restrict__ Freq,
                                                    float* __restrict__ out) {
    __shared__ float2 bufA[4][256];
    __shared__ float2 bufB[4][256];
    __shared__ float2 TW[128];
    int tid = threadIdx.x;
    int lane = tid & 63;
    int sub = tid >> 6;
    fill_tw256(TW, tid);
    int b  = blockIdx.x >> 6;
    int y0 = (blockIdx.x & 63) << 2;

    for (int i = tid; i < FREQ_COLS * 4; i += 256) {
        int col = i >> 2;
        int s   = i & 3;
        bufA[s][col] = Freq[((size_t)(b * FREQ_COLS + col) << 8) + y0 + s];
    }
    __syncthreads();
    for (int k = FREQ_COLS + lane; k < 256; k += 64) {
        float2 v = bufA[sub][256 - k];
        bufA[sub][k] = make_float2(v.x, -v.y);
    }
    __syncthreads();
    fft256(bufA[sub], bufB[sub], TW, lane, +1.f);
    float* dst = out + (((size_t)(b << 8) + y0) << 8);
    const float scale = 1.0f / 65536.0f;
    for (int i = tid; i < 1024; i += 256) {
        dst[i] = bufA[i >> 8][i & 255].x * scale;
    }
}

// ---------------------------------------------------------------------------
extern "C" void kernel_launch(void* const* d_in, const int* in_sizes, int n_in,
                              void* d_out, int out_size, void* d_ws, size_t ws_size,
                              hipStream_t stream) {
    const float* rows   = (const float*)d_in[0];
    const float* shifts = (const float*)d_in[1];
    const float* latent = (const float*)d_in[2];
    const float* coords = (const float*)d_in[3];
    const float* values = (const float*)d_in[4];
    const float* W0     = (const float*)d_in[5];
    const float* b0     = (const float*)d_in[6];
    const float* W1     = (const float*)d_in[7];
    const float* b1     = (const float*)d_in[8];
    const float* W2     = (const float*)d_in[9];
    const float* b2     = (const float*)d_in[10];
    const float* W3     = (const float*)d_in[11];
    const float* b3     = (const float*)d_in[12];
    const float* Wd     = (const float*)d_in[13];
    const float* bd     = (const float*)d_in[14];
    const float* ctf    = (const float*)d_in[15];
    float* out = (float*)d_out;

    // Workspace layout
    char* w = (char*)d_ws;
    size_t off = 0;
    float* bdata = (float*)(w + off);  off += 4096;
    float* img   = (float*)(w + off);  off += (size_t)IMG_ELEMS * 4;
    float2* Freq = (float2*)(w + off); off += (size_t)BB * FREQ_COLS * 256 * 8;
    unsigned* bucket = (unsigned*)(w + off); off += (size_t)NBLK * 4096 * 4;   // 32 MB
    unsigned* lbaseT = (unsigned*)(w + off); off += (size_t)257 * NBLK * 4;    // ~2 MB
    float* partials  = (float*)(w + off);
    size_t fixed = off;

    int M = 0;
    if      (ws_size >= fixed + 8ull * 4194304) M = 8;
    else if (ws_size >= fixed + 4ull * 4194304) M = 4;
    else if (ws_size >= fixed + 2ull * 4194304) M = 2;

    prep_kernel<<<1, 64, 0, stream>>>(rows, shifts, latent,
                                      W0, b0, W1, b1, W2, b2, W3, b3, bdata);

    if (M > 0) {
        fill2_kernel<<<NBLK, 256, 0, stream>>>(coords, values, Wd, bd, bdata,
                                               bucket, lbaseT);
        accum2_kernel<<<256 * M, 256, 0, stream>>>(bucket, lbaseT, partials, M);
    } else {
        int n4 = IMG_ELEMS / 4;
        zero_kernel<<<(n4 + 255) / 256, 256, 0, stream>>>((float4*)img, n4);
        scatter_atomic_kernel<<<NBLK, 256, 0, stream>>>(coords, values, Wd, bd,
                                                        bdata, img);
    }

    fft_rows_fwd<<<BB * 64, 256, 0, stream>>>(img, partials, M, Freq);
    fft_cols_ctf<<<BB * 33, 256, 0, stream>>>(Freq, ctf);
    fft_rows_inv<<<BB * 64, 256, 0, stream>>>(Freq, out);
}

// Round 8
// 229.179 us; speedup vs baseline: 1.2260x; 1.2260x over previous
//
#include <hip/hip_runtime.h>
#include <math.h>

// Problem constants (fixed by reference)
#define BB   16
#define LATD 8
#define NN   500000
#define XSZ  256
#define HALF 128
#define IMG_ELEMS (BB * XSZ * XSZ)          // 1,048,576 floats
#define FREQ_COLS 129                        // XS/2+1
#define NBLK ((NN + 255) / 256)              // 1954 point-blocks

// Entry packing: bits[11:0] = pixel-in-tile, bits[31:12] = top 20 bits of the
// fp32 value (round-to-nearest on the dropped 12 mantissa bits).
__device__ __forceinline__ unsigned pack_entry(float v, int off12) {
    unsigned pv = (__float_as_uint(v) + 0x800u) & 0xFFFFF000u;
    return pv | (unsigned)off12;
}
__device__ __forceinline__ float entry_val(unsigned e) {
    return __uint_as_float(e & 0xFFFFF000u);
}

// ---------------------------------------------------------------------------
// wave64 inclusive scan (shuffle-based, no barriers)
// ---------------------------------------------------------------------------
__device__ __forceinline__ unsigned wave_incl_scan(unsigned x, int lane) {
    #pragma unroll
    for (int d = 1; d < 64; d <<= 1) {
        unsigned y = __shfl_up(x, d, 64);
        if (lane >= d) x += y;
    }
    return x;
}

// ---------------------------------------------------------------------------
// K0: per-image prep — rotation rows 0/1, shifts+half, SIREN MLP hidden h[8]
// ---------------------------------------------------------------------------
__global__ void prep_kernel(const float* __restrict__ rows,
                            const float* __restrict__ shifts,
                            const float* __restrict__ latent,
                            const float* __restrict__ W0, const float* __restrict__ b0,
                            const float* __restrict__ W1, const float* __restrict__ b1,
                            const float* __restrict__ W2, const float* __restrict__ b2,
                            const float* __restrict__ W3, const float* __restrict__ b3,
                            float* __restrict__ bdata) {
    int b = threadIdx.x;
    if (b >= BB) return;

    float rot  = rows[b * 3 + 0];
    float tilt = rows[b * 3 + 1];
    float psi  = rows[b * 3 + 2];
    float ca, sa, cb, sb, cg, sg;
    sincosf(rot, &sa, &ca);
    sincosf(tilt, &sb, &cb);
    sincosf(psi, &sg, &cg);

    float R00 =  cg * cb * ca - sg * sa;
    float R01 =  cg * cb * sa + sg * ca;
    float R02 = -cg * sb;
    float R10 = -sg * cb * ca - cg * sa;
    float R11 = -sg * cb * sa + cg * ca;
    float R12 =  sg * sb;

    float h[LATD], t[LATD];
    #pragma unroll
    for (int j = 0; j < LATD; ++j) {
        float acc = b0[j];
        #pragma unroll
        for (int l = 0; l < LATD; ++l) acc += latent[b * LATD + l] * W0[l * LATD + j];
        t[j] = acc;
    }
    #pragma unroll
    for (int j = 0; j < LATD; ++j) h[j] = sinf(30.0f * t[j]);

    const float* Ws[3] = {W1, W2, W3};
    const float* bs[3] = {b1, b2, b3};
    for (int L = 0; L < 3; ++L) {
        #pragma unroll
        for (int j = 0; j < LATD; ++j) {
            float acc = bs[L][j];
            #pragma unroll
            for (int l = 0; l < LATD; ++l) acc += h[l] * Ws[L][l * LATD + j];
            t[j] = acc;
        }
        #pragma unroll
        for (int j = 0; j < LATD; ++j) h[j] += sinf(t[j]);
    }

    float* P = bdata + b * 16;
    P[0] = R00; P[1] = R01; P[2] = R02;
    P[3] = R10; P[4] = R11; P[5] = R12;
    P[6] = shifts[b * 2 + 0] + (float)HALF;
    P[7] = shifts[b * 2 + 1] + (float)HALF;
    #pragma unroll
    for (int j = 0; j < LATD; ++j) P[8 + j] = h[j];
}

__device__ __forceinline__ int2 project_px(const float* __restrict__ Q,
                                           float cx, float cy, float cz) {
    float x = fmaf(Q[0], cx, fmaf(Q[1], cy, fmaf(Q[2], cz, Q[6])));
    float y = fmaf(Q[3], cx, fmaf(Q[4], cy, fmaf(Q[5], cz, Q[7])));
    float px = fminf(fmaxf(rintf(x), 0.f), 255.f);
    float py = fminf(fmaxf(rintf(y), 0.f), 255.f);
    return make_int2((int)px, (int)py);
}

// ---------------------------------------------------------------------------
// K1: fill3 — LDS-atomic ranking (proven fast in R6), per-block output:
// tile-sorted contiguous 4096-entry segment + lbaseT[blk][257] offset row
// (entry t = start of tile t's run; entry 256 = total). No count/scan
// kernels, no ballots (R7's ballot rank machinery measured ~2x slower than
// ds fetch_add ranking).
// ---------------------------------------------------------------------------
__global__ __launch_bounds__(256) void fill3_kernel(
        const float* __restrict__ coords, const float* __restrict__ values,
        const float* __restrict__ Wd, const float* __restrict__ bd,
        const float* __restrict__ bdata, unsigned* __restrict__ bucket,
        unsigned* __restrict__ lbaseT) {
    __shared__ float    P[256];
    __shared__ unsigned hist[256];
    __shared__ unsigned wsum[4];
    __shared__ unsigned lbase[256];
    __shared__ unsigned stage[4096];

    int tid = threadIdx.x;
    int blk = blockIdx.x;
    int lane = tid & 63;
    int w = tid >> 6;
    P[tid] = bdata[tid];
    hist[tid] = 0;
    __syncthreads();

    int n = blk * 256 + tid;
    bool active = (n < NN);

    unsigned word[BB];
    unsigned rk[BB];
    unsigned char tl[BB];
    if (active) {
        float cx = coords[n * 3 + 0];
        float cy = coords[n * 3 + 1];
        float cz = coords[n * 3 + 2];
        float base = values[n] + bd[n];
        float wd[LATD];
        #pragma unroll
        for (int l = 0; l < LATD; ++l) wd[l] = Wd[l * NN + n];
        #pragma unroll
        for (int bi = 0; bi < BB; ++bi) {
            const float* Q = &P[bi * 16];
            int2 p = project_px(Q, cx, cy, cz);
            float delta = 0.f;
            #pragma unroll
            for (int l = 0; l < LATD; ++l) delta = fmaf(Q[8 + l], wd[l], delta);
            int tile = bi * 16 + (p.y >> 4);
            int off12 = ((p.y & 15) << 8) | p.x;
            word[bi] = pack_entry(base + delta, off12);
            tl[bi] = (unsigned char)tile;
            rk[bi] = atomicAdd(&hist[tile], 1u);
        }
    }
    __syncthreads();

    // exclusive scan of hist (256 counters) via wave shuffles
    unsigned v = hist[tid];
    unsigned s = wave_incl_scan(v, lane);
    if (lane == 63) wsum[w] = s;
    __syncthreads();
    unsigned off = 0;
    #pragma unroll
    for (int i = 0; i < 4; ++i) { unsigned u = wsum[i]; if (i < w) off += u; }
    unsigned excl = s + off - v;
    lbase[tid] = excl;
    __syncthreads();

    if (active) {
        #pragma unroll
        for (int bi = 0; bi < BB; ++bi) {
            stage[lbase[tl[bi]] + rk[bi]] = word[bi];
        }
    }

    int nactive = NN - blk * 256;
    if (nactive > 256) nactive = 256;
    int tot = nactive * BB;

    // offset row (coalesced): lbaseT[blk][t] = run start, [blk][256] = total
    lbaseT[(size_t)blk * 257 + tid] = excl;
    if (tid == 0) lbaseT[(size_t)blk * 257 + 256] = (unsigned)tot;
    __syncthreads();

    unsigned* seg = bucket + ((size_t)blk << 12);
    for (int i = tid; i < tot; i += 256) seg[i] = stage[i];
}

// ---------------------------------------------------------------------------
// K2: accum2b — block (t,m) accumulates tile t over a slice of source
// blocks. Each WAVE takes one source block at a time; lanes read the run
// cooperatively (s+lane, coalesced: 1-2 sectors per ~16-entry run vs 16
// sectors in R7's per-thread walk). LDS atomic accumulate, write partial.
// ---------------------------------------------------------------------------
__global__ __launch_bounds__(256) void accum2b_kernel(
        const unsigned* __restrict__ bucket, const unsigned* __restrict__ lbaseT,
        float* __restrict__ partials, int M) {
    __shared__ float tile[4096];
    int t = blockIdx.x & 255;
    int m = blockIdx.x >> 8;
    int tid = threadIdx.x;
    int lane = tid & 63;
    int w = tid >> 6;
    #pragma unroll
    for (int i = 0; i < 16; ++i) tile[tid + (i << 8)] = 0.f;
    __syncthreads();

    int blk0 = (int)((long long)NBLK * m / M);
    int blk1 = (int)((long long)NBLK * (m + 1) / M);
    for (int B = blk0 + w; B < blk1; B += 4) {
        const unsigned* lrow = lbaseT + (size_t)B * 257;
        unsigned s = lrow[t];         // broadcast (all lanes same addr)
        unsigned e = lrow[t + 1];     // t=255 -> slot 256 = total
        const unsigned* bp = bucket + ((size_t)B << 12);
        for (unsigned i = s + (unsigned)lane; i < e; i += 64) {
            unsigned x = bp[i];
            atomicAdd(&tile[x & 4095u], entry_val(x));
        }
    }
    __syncthreads();
    float4* dst = (float4*)(partials + (((size_t)m * 256 + t) << 12));
    const float4* src = (const float4*)tile;
    for (int i = tid; i < 1024; i += 256) dst[i] = src[i];
}

// ---------------------------------------------------------------------------
// Fallback: device-scope atomic scatter (R1 path) + zero
// ---------------------------------------------------------------------------
__global__ void zero_kernel(float4* __restrict__ p, int n4) {
    int i = blockIdx.x * blockDim.x + threadIdx.x;
    if (i < n4) p[i] = make_float4(0.f, 0.f, 0.f, 0.f);
}

__global__ __launch_bounds__(256) void scatter_atomic_kernel(
        const float* __restrict__ coords, const float* __restrict__ values,
        const float* __restrict__ Wd, const float* __restrict__ bd,
        const float* __restrict__ bdata, float* __restrict__ img) {
    __shared__ float P[BB * 16];
    P[threadIdx.x] = bdata[threadIdx.x];
    __syncthreads();
    int n = blockIdx.x * 256 + threadIdx.x;
    if (n >= NN) return;
    float cx = coords[n * 3 + 0];
    float cy = coords[n * 3 + 1];
    float cz = coords[n * 3 + 2];
    float base = values[n] + bd[n];
    float wd[LATD];
    #pragma unroll
    for (int l = 0; l < LATD; ++l) wd[l] = Wd[l * NN + n];
    #pragma unroll
    for (int b = 0; b < BB; ++b) {
        const float* Q = &P[b * 16];
        int2 p = project_px(Q, cx, cy, cz);
        float delta = 0.f;
        #pragma unroll
        for (int l = 0; l < LATD; ++l) delta = fmaf(Q[8 + l], wd[l], delta);
        atomicAdd(img + ((b << 16) | (p.y << 8) | p.x), base + delta);
    }
}

// ---------------------------------------------------------------------------
// Gaussian 7-tap weights (sigma=1, radius=3, normalized)
// ---------------------------------------------------------------------------
__device__ __constant__ float GW[4] = {0.39905027f, 0.24203623f, 0.05400558f, 0.00443305f};

// ---------------------------------------------------------------------------
// 256-point complex Stockham FFT in LDS, one 64-lane slice per FFT.
// ---------------------------------------------------------------------------
__device__ __forceinline__ void fft256(float2* src, float2* dst,
                                       const float2* __restrict__ TW,
                                       int lane, float dir) {
    #pragma unroll
    for (int t = 0; t < 8; ++t) {
        const int s = 1 << t;
        #pragma unroll
        for (int r = 0; r < 2; ++r) {
            int i = lane + (r << 6);
            int q = i & (s - 1);
            int p = i >> t;
            float2 a = src[q + s * p];
            float2 b = src[q + s * p + 128];
            int m = p << t;
            float cs = TW[m].x;
            float sn = dir * TW[m].y;
            float2 sum = make_float2(a.x + b.x, a.y + b.y);
            float dx = a.x - b.x;
            float dy = a.y - b.y;
            float2 tw = make_float2(dx * cs - dy * sn, dx * sn + dy * cs);
            int o = q + ((p * s) << 1);
            dst[o] = sum;
            dst[o + s] = tw;
        }
        __syncthreads();
        float2* tmp = src; src = dst; dst = tmp;
    }
}

__device__ __forceinline__ void fill_tw256(float2* TW, int tid) {
    if (tid < 128) {
        float sn, cs;
        sincosf(0.0245436926061703f * (float)tid, &sn, &cs);
        TW[tid] = make_float2(cs, sn);
    }
}

// ---------------------------------------------------------------------------
// K3: (sum M partials) + x-blur + forward row rFFT, 4 rows per block.
// ---------------------------------------------------------------------------
__global__ __launch_bounds__(256) void fft_rows_fwd(const float* __restrict__ img,
                                                    const float* __restrict__ partials,
                                                    int M,
                                                    float2* __restrict__ Freq) {
    __shared__ float2 bufA[4][256];
    __shared__ float2 bufB[4][256];
    __shared__ float2 TW[128];
    __shared__ float  rowr[4][256];
    int tid = threadIdx.x;
    int lane = tid & 63;
    int sub = tid >> 6;
    fill_tw256(TW, tid);
    int b  = blockIdx.x >> 6;
    int y0 = (blockIdx.x & 63) << 2;

    if (M > 0) {
        int t = (b << 4) | (y0 >> 4);
        const float* pb = partials + ((size_t)t << 12) + ((y0 & 15) << 8);
        const size_t mstr = (size_t)256 << 12;
        for (int i = tid; i < 1024; i += 256) {
            float s = 0.f;
            for (int m = 0; m < M; ++m) s += pb[(size_t)m * mstr + i];
            ((float*)rowr)[i] = s;
        }
    } else {
        const float* src = img + (((size_t)(b << 8) + y0) << 8);
        for (int i = tid; i < 1024; i += 256) ((float*)rowr)[i] = src[i];
    }
    __syncthreads();

    #pragma unroll
    for (int j = 0; j < 4; ++j) {
        int x = lane + (j << 6);
        float acc = GW[0] * rowr[sub][x];
        #pragma unroll
        for (int t = 1; t <= 3; ++t) {
            if (x - t >= 0)  acc += GW[t] * rowr[sub][x - t];
            if (x + t < 256) acc += GW[t] * rowr[sub][x + t];
        }
        bufA[sub][x] = make_float2(acc, 0.f);
    }
    __syncthreads();
    fft256(bufA[sub], bufB[sub], TW, lane, -1.f);

    for (int i = tid; i < FREQ_COLS * 4; i += 256) {
        int col = i >> 2;
        int s   = i & 3;
        Freq[((size_t)(b * FREQ_COLS + col) << 8) + y0 + s] = bufA[s][col];
    }
}

// ---------------------------------------------------------------------------
// K4: column pass — y-blur (complex) + FFT + CTF + inverse FFT, 4 cols/block.
// ---------------------------------------------------------------------------
__global__ __launch_bounds__(256) void fft_cols_ctf(float2* __restrict__ Freq,
                                                    const float* __restrict__ ctf) {
    __shared__ float2 bufA[4][256];
    __shared__ float2 bufB[4][256];
    __shared__ float2 TW[128];
    int tid = threadIdx.x;
    int lane = tid & 63;
    int sub = tid >> 6;
    fill_tw256(TW, tid);
    int b  = blockIdx.x / 33;
    int c0 = (blockIdx.x - b * 33) << 2;
    int col  = c0 + sub;
    int colc = col < FREQ_COLS ? col : (FREQ_COLS - 1);
    float2* basep = Freq + ((size_t)(b * FREQ_COLS + colc) << 8);

    #pragma unroll
    for (int j = 0; j < 4; ++j) {
        int k = lane + (j << 6);
        bufB[sub][k] = basep[k];
    }
    __syncthreads();
    #pragma unroll
    for (int j = 0; j < 4; ++j) {
        int k = lane + (j << 6);
        float ax = GW[0] * bufB[sub][k].x;
        float ay = GW[0] * bufB[sub][k].y;
        #pragma unroll
        for (int t = 1; t <= 3; ++t) {
            if (k - t >= 0)  { ax += GW[t] * bufB[sub][k - t].x; ay += GW[t] * bufB[sub][k - t].y; }
            if (k + t < 256) { ax += GW[t] * bufB[sub][k + t].x; ay += GW[t] * bufB[sub][k + t].y; }
        }
        bufA[sub][k] = make_float2(ax, ay);
    }
    __syncthreads();
    fft256(bufA[sub], bufB[sub], TW, lane, -1.f);
    #pragma unroll
    for (int j = 0; j < 4; ++j) {
        int k = lane + (j << 6);
        float c = ctf[(size_t)((b << 8) | k) * FREQ_COLS + colc];
        bufA[sub][k].x *= c;
        bufA[sub][k].y *= c;
    }
    __syncthreads();
    fft256(bufA[sub], bufB[sub], TW, lane, +1.f);
    if (col < FREQ_COLS) {
        #pragma unroll
        for (int j = 0; j < 4; ++j) {
            int k = lane + (j << 6);
            basep[k] = bufA[sub][k];
        }
    }
}

// ---------------------------------------------------------------------------
// K5: Hermitian-extend + inverse row FFT + scale, 4 rows per block.
// ---------------------------------------------------------------------------
__global__ __launch_bounds__(256) void fft_rows_inv(const float2* __restrict__ Freq,
                                                    float* __restrict__ out) {
    __shared__ float2 bufA[4][256];
    __shared__ float2 bufB[4][256];
    __shared__ float2 TW[128];
    int tid = threadIdx.x;
    int lane = tid & 63;
    int sub = tid >> 6;
    fill_tw256(TW, tid);
    int b  = blockIdx.x >> 6;
    int y0 = (blockIdx.x & 63) << 2;

    for (int i = tid; i < FREQ_COLS * 4; i += 256) {
        int col = i >> 2;
        int s   = i & 3;
        bufA[s][col] = Freq[((size_t)(b * FREQ_COLS + col) << 8) + y0 + s];
    }
    __syncthreads();
    for (int k = FREQ_COLS + lane; k < 256; k += 64) {
        float2 v = bufA[sub][256 - k];
        bufA[sub][k] = make_float2(v.x, -v.y);
    }
    __syncthreads();
    fft256(bufA[sub], bufB[sub], TW, lane, +1.f);
    float* dst = out + (((size_t)(b << 8) + y0) << 8);
    const float scale = 1.0f / 65536.0f;
    for (int i = tid; i < 1024; i += 256) {
        dst[i] = bufA[i >> 8][i & 255].x * scale;
    }
}

// ---------------------------------------------------------------------------
extern "C" void kernel_launch(void* const* d_in, const int* in_sizes, int n_in,
                              void* d_out, int out_size, void* d_ws, size_t ws_size,
                              hipStream_t stream) {
    const float* rows   = (const float*)d_in[0];
    const float* shifts = (const float*)d_in[1];
    const float* latent = (const float*)d_in[2];
    const float* coords = (const float*)d_in[3];
    const float* values = (const float*)d_in[4];
    const float* W0     = (const float*)d_in[5];
    const float* b0     = (const float*)d_in[6];
    const float* W1     = (const float*)d_in[7];
    const float* b1     = (const float*)d_in[8];
    const float* W2     = (const float*)d_in[9];
    const float* b2     = (const float*)d_in[10];
    const float* W3     = (const float*)d_in[11];
    const float* b3     = (const float*)d_in[12];
    const float* Wd     = (const float*)d_in[13];
    const float* bd     = (const float*)d_in[14];
    const float* ctf    = (const float*)d_in[15];
    float* out = (float*)d_out;

    // Workspace layout
    char* w = (char*)d_ws;
    size_t off = 0;
    float* bdata = (float*)(w + off);  off += 4096;
    float* img   = (float*)(w + off);  off += (size_t)IMG_ELEMS * 4;
    float2* Freq = (float2*)(w + off); off += (size_t)BB * FREQ_COLS * 256 * 8;
    unsigned* bucket = (unsigned*)(w + off); off += (size_t)NBLK * 4096 * 4;   // 32 MB
    unsigned* lbaseT = (unsigned*)(w + off); off += (size_t)NBLK * 257 * 4;    // ~2 MB
    float* partials  = (float*)(w + off);
    size_t fixed = off;

    int M = 0;
    if      (ws_size >= fixed + 4ull * 4194304) M = 4;
    else if (ws_size >= fixed + 2ull * 4194304) M = 2;

    prep_kernel<<<1, 64, 0, stream>>>(rows, shifts, latent,
                                      W0, b0, W1, b1, W2, b2, W3, b3, bdata);

    if (M > 0) {
        fill3_kernel<<<NBLK, 256, 0, stream>>>(coords, values, Wd, bd, bdata,
                                               bucket, lbaseT);
        accum2b_kernel<<<256 * M, 256, 0, stream>>>(bucket, lbaseT, partials, M);
    } else {
        int n4 = IMG_ELEMS / 4;
        zero_kernel<<<(n4 + 255) / 256, 256, 0, stream>>>((float4*)img, n4);
        scatter_atomic_kernel<<<NBLK, 256, 0, stream>>>(coords, values, Wd, bd,
                                                        bdata, img);
    }

    fft_rows_fwd<<<BB * 64, 256, 0, stream>>>(img, partials, M, Freq);
    fft_cols_ctf<<<BB * 33, 256, 0, stream>>>(Freq, ctf);
    fft_rows_inv<<<BB * 64, 256, 0, stream>>>(Freq, out);
}